// Round 2
// baseline (2151.162 us; speedup 1.0000x reference)
//
#include <hip/hip_runtime.h>
#include <math.h>

#define TILE 128
#define BK 64

typedef __bf16 bf16x8 __attribute__((ext_vector_type(8)));
typedef float f32x4 __attribute__((ext_vector_type(4)));
typedef short short8 __attribute__((ext_vector_type(8)));
typedef unsigned int uint2v __attribute__((ext_vector_type(2)));

__device__ __forceinline__ float bf2f(unsigned short u) {
  union { unsigned int i; float f; } v; v.i = ((unsigned int)u) << 16; return v.f;
}
__device__ __forceinline__ unsigned short f2bf(float f) {
  union { float fl; unsigned int i; } v; v.fl = f;
  unsigned int x = v.i;
  return (unsigned short)((x + 0x7FFFu + ((x >> 16) & 1u)) >> 16);  // RNE
}
// pack 2 f32 -> 2 bf16 (RNE), one VALU instr
__device__ __forceinline__ unsigned int cvt_pk_bf16(float lo, float hi) {
  unsigned int r;
  asm("v_cvt_pk_bf16_f32 %0, %1, %2" : "=v"(r) : "v"(lo), "v"(hi));
  return r;
}

// C[M,N] = alpha * (A[M,K] @ B[N,K]^T) + bias[col]; f32 accum.
// AF32/BF32: source dtype f32 (else bf16). CF32: output f32 (else bf16).
// Batched via blockIdx.z: base = (z / nXi) * sXo + (z % nXi) * sXi
template<int AF32, int BF32, int CF32, int HAS_BIAS>
__global__ __launch_bounds__(256, 2)
void gemm_bt(const void* __restrict__ Av, const void* __restrict__ Bv,
             const float* __restrict__ bias, void* __restrict__ Cv,
             int M, int N, int K, int lda, int ldb, int ldc,
             long sAo, long sAi, int nAi,
             long sBo, long sBi, int nBi,
             long sCo, long sCi, int nCi,
             float alpha)
{
  __shared__ alignas(16) unsigned short lA[TILE * BK];
  __shared__ alignas(16) unsigned short lB[TILE * BK];

  const int z = blockIdx.z;
  const long offA = (long)(z / nAi) * sAo + (long)(z % nAi) * sAi;
  const long offB = (long)(z / nBi) * sBo + (long)(z % nBi) * sBi;
  const long offC = (long)(z / nCi) * sCo + (long)(z % nCi) * sCi;

  const int tm = blockIdx.y * TILE;
  const int tn = blockIdx.x * TILE;
  const int tid = (int)threadIdx.x;
  const int lane = tid & 63;
  const int wave = tid >> 6;
  const int wm = (wave >> 1) * 64;
  const int wn = (wave & 1) * 64;
  const int l16 = lane & 15;
  const int kg = lane >> 4;

  f32x4 acc[4][4];
  #pragma unroll
  for (int i = 0; i < 4; ++i)
    #pragma unroll
    for (int j = 0; j < 4; ++j)
      #pragma unroll
      for (int e = 0; e < 4; ++e) acc[i][j][e] = 0.f;

  // bf16-source staging coords
  const int srow = tid >> 3;          // 0..31 (+32/iter)
  const int sc8 = (tid & 7) * 8;
  // f32-source staging coords
  const int frow = tid >> 4;          // 0..15 (+16/iter)
  const int fc4 = (tid & 15) * 4;

  const int fbA = (wm + l16) * BK + kg * 8;
  const int fbB = (wn + l16) * BK + kg * 8;

  const unsigned short* A16 = (const unsigned short*)Av + (AF32 ? 0 : offA);
  const unsigned short* B16 = (const unsigned short*)Bv + (BF32 ? 0 : offB);
  const float* A32 = (const float*)Av + (AF32 ? offA : 0);
  const float* B32 = (const float*)Bv + (BF32 ? offB : 0);

  for (int k0 = 0; k0 < K; k0 += BK) {
    short8 ra16[4], rb16[4];
    uint2v ra32[8], rb32[8];
    if (AF32) {
      #pragma unroll
      for (int i = 0; i < 8; ++i) {
        f32x4 v = *(const f32x4*)(A32 + (long)(tm + frow + i * 16) * lda + k0 + fc4);
        ra32[i][0] = cvt_pk_bf16(v[0], v[1]);
        ra32[i][1] = cvt_pk_bf16(v[2], v[3]);
      }
    } else {
      #pragma unroll
      for (int i = 0; i < 4; ++i)
        ra16[i] = *(const short8*)(A16 + (long)(tm + srow + i * 32) * lda + k0 + sc8);
    }
    if (BF32) {
      #pragma unroll
      for (int i = 0; i < 8; ++i) {
        f32x4 v = *(const f32x4*)(B32 + (long)(tn + frow + i * 16) * ldb + k0 + fc4);
        rb32[i][0] = cvt_pk_bf16(v[0], v[1]);
        rb32[i][1] = cvt_pk_bf16(v[2], v[3]);
      }
    } else {
      #pragma unroll
      for (int i = 0; i < 4; ++i)
        rb16[i] = *(const short8*)(B16 + (long)(tn + srow + i * 32) * ldb + k0 + sc8);
    }
    __syncthreads();
    if (AF32) {
      #pragma unroll
      for (int i = 0; i < 8; ++i)
        *(uint2v*)&lA[(frow + i * 16) * BK + fc4] = ra32[i];
    } else {
      #pragma unroll
      for (int i = 0; i < 4; ++i)
        *(short8*)&lA[(srow + i * 32) * BK + sc8] = ra16[i];
    }
    if (BF32) {
      #pragma unroll
      for (int i = 0; i < 8; ++i)
        *(uint2v*)&lB[(frow + i * 16) * BK + fc4] = rb32[i];
    } else {
      #pragma unroll
      for (int i = 0; i < 4; ++i)
        *(short8*)&lB[(srow + i * 32) * BK + sc8] = rb16[i];
    }
    __syncthreads();
    #pragma unroll
    for (int kk = 0; kk < 2; ++kk) {
      bf16x8 af[4], bfr[4];
      #pragma unroll
      for (int mi = 0; mi < 4; ++mi)
        af[mi] = *(const bf16x8*)&lA[fbA + mi * 16 * BK + kk * 32];
      #pragma unroll
      for (int ni = 0; ni < 4; ++ni)
        bfr[ni] = *(const bf16x8*)&lB[fbB + ni * 16 * BK + kk * 32];
      #pragma unroll
      for (int mi = 0; mi < 4; ++mi)
        #pragma unroll
        for (int ni = 0; ni < 4; ++ni)
          acc[mi][ni] = __builtin_amdgcn_mfma_f32_16x16x32_bf16(
              af[mi], bfr[ni], acc[mi][ni], 0, 0, 0);
    }
  }

  unsigned short* C16 = (unsigned short*)Cv + (CF32 ? 0 : offC);
  float* C32 = (float*)Cv + (CF32 ? offC : 0);
  // C/D layout (m89-verified): col = lane&15, row = (lane>>4)*4 + j
  #pragma unroll
  for (int ni = 0; ni < 4; ++ni) {
    int col = tn + wn + ni * 16 + l16;
    float bv = HAS_BIAS ? bias[col] : 0.f;
    #pragma unroll
    for (int mi = 0; mi < 4; ++mi) {
      #pragma unroll
      for (int j = 0; j < 4; ++j) {
        int row = tm + wm + mi * 16 + kg * 4 + j;
        float v = acc[mi][ni][j] * alpha + bv;
        if (CF32) C32[(long)row * ldc + col] = v;
        else      C16[(long)row * ldc + col] = f2bf(v);
      }
    }
  }
}

// In-place LayerNorm over rows of 512 bf16 elems. One wave per row. g,b f32.
__global__ __launch_bounds__(256)
void ln_rows(unsigned short* __restrict__ t,
             const float* __restrict__ g,
             const float* __restrict__ b)
{
  const int row = blockIdx.x * 4 + ((int)threadIdx.x >> 6);
  const int lane = (int)threadIdx.x & 63;
  unsigned short* p = t + (long)row * 512 + lane * 8;
  short8 rv = *(const short8*)p;
  float x[8];
  #pragma unroll
  for (int j = 0; j < 8; ++j) x[j] = bf2f((unsigned short)rv[j]);
  float s = 0.f;
  #pragma unroll
  for (int j = 0; j < 8; ++j) s += x[j];
  #pragma unroll
  for (int off = 32; off > 0; off >>= 1) s += __shfl_xor(s, off, 64);
  float mu = s * (1.f / 512.f);
  float vs = 0.f;
  #pragma unroll
  for (int j = 0; j < 8; ++j) { float d = x[j] - mu; vs += d * d; }
  #pragma unroll
  for (int off = 32; off > 0; off >>= 1) vs += __shfl_xor(vs, off, 64);
  float rs = rsqrtf(vs * (1.f / 512.f) + 1e-5f);
  f32x4 gv0 = *(const f32x4*)(g + lane * 8);
  f32x4 gv1 = *(const f32x4*)(g + lane * 8 + 4);
  f32x4 bv0 = *(const f32x4*)(b + lane * 8);
  f32x4 bv1 = *(const f32x4*)(b + lane * 8 + 4);
  short8 ov;
  #pragma unroll
  for (int j = 0; j < 4; ++j)
    ov[j] = (short)f2bf((x[j] - mu) * rs * gv0[j] + bv0[j]);
  #pragma unroll
  for (int j = 0; j < 4; ++j)
    ov[4 + j] = (short)f2bf((x[4 + j] - mu) * rs * gv1[j] + bv1[j]);
  *(short8*)p = ov;
}

// w = (val * gelu_exact(gate)) / max(||.||2, 1e-12); h rows are 1024 (val|gate)
__global__ __launch_bounds__(256)
void gate_norm(const unsigned short* __restrict__ h, unsigned short* __restrict__ w)
{
  const int row = blockIdx.x * 4 + ((int)threadIdx.x >> 6);
  const int lane = (int)threadIdx.x & 63;
  const unsigned short* hp = h + (long)row * 1024 + lane * 8;
  short8 vv = *(const short8*)hp;
  short8 gg = *(const short8*)(hp + 512);
  float wv[8];
  float ssq = 0.f;
  #pragma unroll
  for (int j = 0; j < 8; ++j) {
    float val = bf2f((unsigned short)vv[j]);
    float gt  = bf2f((unsigned short)gg[j]);
    float ge  = 0.5f * gt * (1.f + erff(gt * 0.70710678118654752f));
    float tt  = val * ge;
    wv[j] = tt;
    ssq += tt * tt;
  }
  #pragma unroll
  for (int off = 32; off > 0; off >>= 1) ssq += __shfl_xor(ssq, off, 64);
  float scale = 1.f / fmaxf(sqrtf(ssq), 1e-12f);
  short8 ov;
  #pragma unroll
  for (int j = 0; j < 8; ++j) ov[j] = (short)f2bf(wv[j] * scale);
  *(short8*)(w + (long)row * 512 + lane * 8) = ov;
}

// v (B,S,E) bf16 -> vT (B*H, 512d, 512t), 64x64 LDS tiles
__global__ __launch_bounds__(256)
void transpose_v(const unsigned short* __restrict__ v, unsigned short* __restrict__ vT)
{
  __shared__ alignas(16) unsigned short lt[64][72];
  const int bh = blockIdx.z;
  const int b = bh >> 3, hh = bh & 7;
  const int d0 = blockIdx.x * 64, t0 = blockIdx.y * 64;
  const int tid = (int)threadIdx.x;
  const unsigned short* src = v + (long)b * (512L * 4096L) + hh * 512;
  #pragma unroll
  for (int it = 0; it < 2; ++it) {
    int ci = it * 256 + tid;
    int r = ci >> 3, c8 = (ci & 7) * 8;
    short8 val = *(const short8*)(src + (long)(t0 + r) * 4096 + d0 + c8);
    *(short8*)&lt[r][c8] = val;
  }
  __syncthreads();
  unsigned short* dst = vT + ((long)bh * 512 + d0) * 512 + t0;
  #pragma unroll
  for (int it = 0; it < 2; ++it) {
    int ci = it * 256 + tid;
    int rr = ci >> 3, c8 = (ci & 7) * 8;
    short8 o;
    #pragma unroll
    for (int j = 0; j < 8; ++j) o[j] = (short)lt[c8 + j][rr];
    *(short8*)(dst + (long)rr * 512 + c8) = o;
  }
}

extern "C" void kernel_launch(void* const* d_in, const int* in_sizes, int n_in,
                              void* d_out, int out_size, void* d_ws, size_t ws_size,
                              hipStream_t stream)
{
  (void)in_sizes; (void)n_in; (void)out_size; (void)ws_size;
  const float* x   = (const float*)d_in[0];
  const float* Wq  = (const float*)d_in[1];
  const float* bq  = (const float*)d_in[2];
  const float* Wk  = (const float*)d_in[3];
  const float* bk  = (const float*)d_in[4];
  const float* Wv  = (const float*)d_in[5];
  const float* bv  = (const float*)d_in[6];
  const float* g_q = (const float*)d_in[7];
  const float* b_q = (const float*)d_in[8];
  const float* g_k = (const float*)d_in[9];
  const float* b_k = (const float*)d_in[10];
  const float* Wg  = (const float*)d_in[11];
  const float* bg  = (const float*)d_in[12];
  const float* Wo  = (const float*)d_in[13];
  const float* bo  = (const float*)d_in[14];
  float* out = (float*)d_out;

  const long NE = 33554432L;  // B*S*E
  unsigned short* ws   = (unsigned short*)d_ws;
  unsigned short* qbuf = ws;            // (B,S,E) bf16
  unsigned short* kbuf = ws + NE;       // (B,S,E) bf16
  unsigned short* vbuf = ws + 2 * NE;   // (B,S,E) bf16
  unsigned short* sbuf = ws + 3 * NE;   // (B*H,512,512) bf16 scores
  unsigned short* hbuf = ws + 4 * NE;   // (B*H,512,1024) bf16, 2*NE elems
  unsigned short* wbuf = qbuf;          // reuse (q dead after scores)
  unsigned short* vT   = kbuf;          // reuse (k dead after scores)
  unsigned short* obuf = sbuf;          // reuse (scores dead after h)

  dim3 blk(256);
  const float inv_sqrt_hd = 0.044194173824159216f;  // 1/sqrt(512)

  // q,k,v projections: (8192x4096) = x @ W^T + b   (f32 in -> bf16 out)
  gemm_bt<1, 1, 0, 1><<<dim3(32, 64, 1), blk, 0, stream>>>(x, Wq, bq, qbuf,
      8192, 4096, 4096, 4096, 4096, 4096,
      0L, 0L, 1, 0L, 0L, 1, 0L, 0L, 1, 1.f);
  gemm_bt<1, 1, 0, 1><<<dim3(32, 64, 1), blk, 0, stream>>>(x, Wk, bk, kbuf,
      8192, 4096, 4096, 4096, 4096, 4096,
      0L, 0L, 1, 0L, 0L, 1, 0L, 0L, 1, 1.f);
  gemm_bt<1, 1, 0, 1><<<dim3(32, 64, 1), blk, 0, stream>>>(x, Wv, bv, vbuf,
      8192, 4096, 4096, 4096, 4096, 4096,
      0L, 0L, 1, 0L, 0L, 1, 0L, 0L, 1, 1.f);

  // per-(b,s,h) layernorm over HD=512 (in place)
  ln_rows<<<16384, blk, 0, stream>>>(qbuf, g_q, b_q);
  ln_rows<<<16384, blk, 0, stream>>>(kbuf, g_k, b_k);

  // scores = q @ k^T / sqrt(HD), per (b,h)
  gemm_bt<0, 0, 0, 0><<<dim3(4, 4, 128), blk, 0, stream>>>(qbuf, kbuf, nullptr, sbuf,
      512, 512, 512, 4096, 4096, 512,
      2097152L, 512L, 8,
      2097152L, 512L, 8,
      262144L, 0L, 1,
      inv_sqrt_hd);

  transpose_v<<<dim3(8, 8, 128), blk, 0, stream>>>(vbuf, vT);

  // h = scores @ Wg^T + bg  (N=1024, Wg f32)
  gemm_bt<0, 1, 0, 1><<<dim3(8, 4, 128), blk, 0, stream>>>(sbuf, Wg, bg, hbuf,
      512, 1024, 512, 512, 512, 1024,
      262144L, 0L, 1,
      0L, 0L, 1,
      524288L, 0L, 1,
      1.f);

  // w = normalize(val * gelu(gate))
  gate_norm<<<16384, blk, 0, stream>>>(hbuf, wbuf);

  // attn_out = w @ vT^T, written into (B,S,E) layout
  gemm_bt<0, 0, 0, 0><<<dim3(4, 4, 128), blk, 0, stream>>>(wbuf, vT, nullptr, obuf,
      512, 512, 512, 512, 512, 4096,
      262144L, 0L, 1,
      262144L, 0L, 1,
      2097152L, 512L, 8,
      1.f);

  // final = attn_out @ Wo^T + bo -> d_out (f32)
  gemm_bt<0, 1, 1, 1><<<dim3(32, 64, 1), blk, 0, stream>>>(obuf, Wo, bo, out,
      8192, 4096, 4096, 4096, 4096, 4096,
      0L, 0L, 1, 0L, 0L, 1, 0L, 0L, 1, 1.f);
}

// Round 3
// 1450.009 us; speedup vs baseline: 1.4836x; 1.4836x over previous
//
#include <hip/hip_runtime.h>
#include <math.h>

#define TILE 128
#define BK 64

typedef __bf16 bf16x8 __attribute__((ext_vector_type(8)));
typedef float f32x4 __attribute__((ext_vector_type(4)));
typedef short short8 __attribute__((ext_vector_type(8)));
typedef unsigned int uint2v __attribute__((ext_vector_type(2)));
typedef unsigned int uint4v __attribute__((ext_vector_type(4)));

__device__ __forceinline__ float bf2f(unsigned short u) {
  union { unsigned int i; float f; } v; v.i = ((unsigned int)u) << 16; return v.f;
}
__device__ __forceinline__ unsigned short f2bf(float f) {
  union { float fl; unsigned int i; } v; v.fl = f;
  unsigned int x = v.i;
  return (unsigned short)((x + 0x7FFFu + ((x >> 16) & 1u)) >> 16);  // RNE
}
__device__ __forceinline__ unsigned int cvt_pk_bf16(float lo, float hi) {
  unsigned int r;
  asm("v_cvt_pk_bf16_f32 %0, %1, %2" : "=v"(r) : "v"(lo), "v"(hi));
  return r;
}
// async global->LDS, 16B per lane. lds ptr must be wave-uniform (HW adds lane*16).
__device__ __forceinline__ void gl_lds16(const unsigned short* g, void* l) {
  __builtin_amdgcn_global_load_lds(
      (const __attribute__((address_space(1))) unsigned int*)g,
      (__attribute__((address_space(3))) unsigned int*)l, 16, 0, 0);
}

// ============================================================================
// 256x256 8-phase bf16 GEMM (T1..T5): C = A[M,K] @ B[N,K]^T + bias
// 512 thr (8 waves 2Mx4N), BK=64, 128KiB LDS dbuf, global_load_lds staging
// with pre-swizzled source (XOR ((row&7)<<4)), counted vmcnt.
// ============================================================================
template<int CF32, int HAS_BIAS>
__global__ __launch_bounds__(512)
void gemm256(const unsigned short* __restrict__ A,
             const unsigned short* __restrict__ B,
             const float* __restrict__ bias,
             void* __restrict__ Cv,
             int M, int N, int K, int lda, int ldb, int ldc, int nbn)
{
  __shared__ alignas(16) unsigned char LDS[131072];
  const int NT = K >> 6;

  // XCD-chunked swizzle (gridDim.x % 8 == 0)
  const int nwg = (int)gridDim.x;
  const int bid = (int)blockIdx.x;
  const int swz = (bid & 7) * (nwg >> 3) + (bid >> 3);
  const int tm = (swz / nbn) * 256;
  const int tn = (swz % nbn) * 256;

  const int tid = (int)threadIdx.x;
  const int lane = tid & 63;
  const int wv = tid >> 6;      // 0..7
  const int wm = wv >> 2;       // 0..1 (A half)
  const int wn = wv & 3;        // 0..3
  const int l16 = lane & 15;
  const int kg = lane >> 4;

  // staging: thread covers linear LDS offset o = i*8192 + tid*16 within a
  // 16KiB half-tile; content[o] = logical[o ^ ((row&7)<<4)], row = o>>7.
  const int srow = tid >> 3;                                   // 0..63 (+64 per i)
  const int scolb = ((tid & 7) * 16) ^ (((tid >> 3) & 7) << 4); // swizzled byte col
  const unsigned short* Abase = A + (long)tm * lda + (scolb >> 1);
  const unsigned short* Bbase = B + (long)tn * ldb + (scolb >> 1);
  const int ldsw = (tid >> 6) * 1024;  // wave-uniform chunk

  // ds_read swizzled cols (row&7 == l16&7 for all frags)
  const int colswz0 = (kg * 16) ^ ((l16 & 7) << 4);
  const int colswz1 = (64 + kg * 16) ^ ((l16 & 7) << 4);

  f32x4 acc[8][4];
  #pragma unroll
  for (int i = 0; i < 8; ++i)
    #pragma unroll
    for (int j = 0; j < 4; ++j)
      #pragma unroll
      for (int e = 0; e < 4; ++e) acc[i][j][e] = 0.f;

  // stage A tile t (both halves, 4 loads) / B half (2 loads)
  auto stageA = [&](int t) {
    const int buf = t & 1;
    #pragma unroll
    for (int h = 0; h < 2; ++h)
      #pragma unroll
      for (int i = 0; i < 2; ++i)
        gl_lds16(Abase + (long)(h * 128 + srow + i * 64) * lda + t * 64,
                 &LDS[buf * 32768 + h * 16384 + i * 8192 + ldsw]);
  };
  auto stageBh = [&](int t, int h) {
    const int buf = t & 1;
    #pragma unroll
    for (int i = 0; i < 2; ++i)
      gl_lds16(Bbase + (long)(h * 128 + srow + i * 64) * ldb + t * 64,
               &LDS[65536 + buf * 32768 + h * 16384 + i * 8192 + ldsw]);
  };

  // prologue: tiles 0 and 1 fully staged; wait tile 0 (8 newest in flight)
  stageA(0); stageBh(0, 0); stageBh(0, 1);
  stageA(1); stageBh(1, 0); stageBh(1, 1);
  asm volatile("s_waitcnt vmcnt(8)" ::: "memory");
  __builtin_amdgcn_s_barrier();

  for (int t = 0; t < NT; ++t) {
    const unsigned char* aB = &LDS[(t & 1) * 32768 + wm * 16384];
    const unsigned char* bB = &LDS[65536 + (t & 1) * 32768 + (wn >> 1) * 16384];
    const int brow = (wn & 1) * 64;
    bf16x8 bfrag[4][2];
    #pragma unroll
    for (int j = 0; j < 4; ++j) {
      // ds-load register subtile (A rows for this C-quadrant)
      bf16x8 a0k0 = *(const bf16x8*)(aB + ((2 * j + 0) * 16 + l16) * 128 + colswz0);
      bf16x8 a0k1 = *(const bf16x8*)(aB + ((2 * j + 0) * 16 + l16) * 128 + colswz1);
      bf16x8 a1k0 = *(const bf16x8*)(aB + ((2 * j + 1) * 16 + l16) * 128 + colswz0);
      bf16x8 a1k1 = *(const bf16x8*)(aB + ((2 * j + 1) * 16 + l16) * 128 + colswz1);
      if (j == 0) {
        #pragma unroll
        for (int ni = 0; ni < 4; ++ni) {
          bfrag[ni][0] = *(const bf16x8*)(bB + (brow + ni * 16 + l16) * 128 + colswz0);
          bfrag[ni][1] = *(const bf16x8*)(bB + (brow + ni * 16 + l16) * 128 + colswz1);
        }
        if (t > 0 && t + 1 < NT) stageA(t + 1);      // A(t+1): slot free (tile t-1 done)
      } else if (j == 1) {
        if (t + 2 < NT) stageBh(t + 2, 0);           // B slot free: B(t) read at j==0
      } else if (j == 2) {
        if (t + 2 < NT) stageBh(t + 2, 1);
      }
      __builtin_amdgcn_s_barrier();
      asm volatile("s_waitcnt lgkmcnt(0)" ::: "memory");
      __builtin_amdgcn_sched_barrier(0);
      __builtin_amdgcn_s_setprio(1);
      #pragma unroll
      for (int ni = 0; ni < 4; ++ni) {
        acc[2 * j + 0][ni] = __builtin_amdgcn_mfma_f32_16x16x32_bf16(a0k0, bfrag[ni][0], acc[2 * j + 0][ni], 0, 0, 0);
        acc[2 * j + 0][ni] = __builtin_amdgcn_mfma_f32_16x16x32_bf16(a0k1, bfrag[ni][1], acc[2 * j + 0][ni], 0, 0, 0);
        acc[2 * j + 1][ni] = __builtin_amdgcn_mfma_f32_16x16x32_bf16(a1k0, bfrag[ni][0], acc[2 * j + 1][ni], 0, 0, 0);
        acc[2 * j + 1][ni] = __builtin_amdgcn_mfma_f32_16x16x32_bf16(a1k1, bfrag[ni][1], acc[2 * j + 1][ni], 0, 0, 0);
      }
      __builtin_amdgcn_s_setprio(0);
      if (j == 3) {
        // boundary: A(t+1),B(t+1) must land; B(t+2) (4 loads) may stay in flight
        if (t >= NT - 2) { asm volatile("s_waitcnt vmcnt(0)" ::: "memory"); }
        else             { asm volatile("s_waitcnt vmcnt(4)" ::: "memory"); }
        __builtin_amdgcn_sched_barrier(0);
      }
      __builtin_amdgcn_s_barrier();
    }
  }

  // epilogue: C/D layout col=l16, row=kg*4+jj (m89-verified)
  const int crow0 = tm + wm * 128 + kg * 4;
  const int ccol0 = tn + wn * 64 + l16;
  #pragma unroll
  for (int ni = 0; ni < 4; ++ni) {
    const int col = ccol0 + ni * 16;
    const float bv = HAS_BIAS ? bias[col] : 0.f;
    #pragma unroll
    for (int mi = 0; mi < 8; ++mi) {
      #pragma unroll
      for (int jj = 0; jj < 4; ++jj) {
        const int row = crow0 + mi * 16 + jj;
        const float v = acc[mi][ni][jj] + bv;
        if (CF32) ((float*)Cv)[(long)row * ldc + col] = v;
        else ((unsigned short*)Cv)[(long)row * ldc + col] = f2bf(v);
      }
    }
  }
}

// ============================================================================
// f32 -> bf16 convert (vectorized, grid-stride), n8 = n/8
// ============================================================================
__global__ __launch_bounds__(256)
void cvt_bf16(const float* __restrict__ in, unsigned short* __restrict__ out, long n8)
{
  long i = (long)blockIdx.x * 256 + threadIdx.x;
  const long stride = (long)gridDim.x * 256;
  for (; i < n8; i += stride) {
    f32x4 v0 = *(const f32x4*)(in + i * 8);
    f32x4 v1 = *(const f32x4*)(in + i * 8 + 4);
    uint4v o;
    o[0] = cvt_pk_bf16(v0[0], v0[1]);
    o[1] = cvt_pk_bf16(v0[2], v0[3]);
    o[2] = cvt_pk_bf16(v1[0], v1[1]);
    o[3] = cvt_pk_bf16(v1[2], v1[3]);
    *(uint4v*)(out + i * 8) = o;
  }
}

// ============================================================================
// 128x128 bf16 GEMM (R2-proven) for small batched stages
// ============================================================================
template<int HAS_BIAS>
__global__ __launch_bounds__(256, 2)
void gemm_bt(const unsigned short* __restrict__ A, const unsigned short* __restrict__ B,
             const float* __restrict__ bias, unsigned short* __restrict__ C,
             int M, int N, int K, int lda, int ldb, int ldc,
             long sAo, long sAi, int nAi,
             long sBo, long sBi, int nBi,
             long sCo, long sCi, int nCi,
             float alpha)
{
  __shared__ alignas(16) unsigned short lA[TILE * BK];
  __shared__ alignas(16) unsigned short lB[TILE * BK];

  const int z = blockIdx.z;
  const unsigned short* Ab = A + (long)(z / nAi) * sAo + (long)(z % nAi) * sAi;
  const unsigned short* Bb = B + (long)(z / nBi) * sBo + (long)(z % nBi) * sBi;
  unsigned short* Cb = C + (long)(z / nCi) * sCo + (long)(z % nCi) * sCi;

  const int tm = blockIdx.y * TILE;
  const int tn = blockIdx.x * TILE;
  const int tid = (int)threadIdx.x;
  const int lane = tid & 63;
  const int wave = tid >> 6;
  const int wm = (wave >> 1) * 64;
  const int wn = (wave & 1) * 64;
  const int l16 = lane & 15;
  const int kg = lane >> 4;

  f32x4 acc[4][4];
  #pragma unroll
  for (int i = 0; i < 4; ++i)
    #pragma unroll
    for (int j = 0; j < 4; ++j)
      #pragma unroll
      for (int e = 0; e < 4; ++e) acc[i][j][e] = 0.f;

  const int srow = tid >> 3;
  const int sc8 = (tid & 7) * 8;
  const int fbA = (wm + l16) * BK + kg * 8;
  const int fbB = (wn + l16) * BK + kg * 8;

  for (int k0 = 0; k0 < K; k0 += BK) {
    short8 ra[4], rb[4];
    #pragma unroll
    for (int i = 0; i < 4; ++i) {
      ra[i] = *(const short8*)(Ab + (long)(tm + srow + i * 32) * lda + k0 + sc8);
      rb[i] = *(const short8*)(Bb + (long)(tn + srow + i * 32) * ldb + k0 + sc8);
    }
    __syncthreads();
    #pragma unroll
    for (int i = 0; i < 4; ++i) {
      *(short8*)&lA[(srow + i * 32) * BK + sc8] = ra[i];
      *(short8*)&lB[(srow + i * 32) * BK + sc8] = rb[i];
    }
    __syncthreads();
    #pragma unroll
    for (int kk = 0; kk < 2; ++kk) {
      bf16x8 af[4], bfr[4];
      #pragma unroll
      for (int mi = 0; mi < 4; ++mi)
        af[mi] = *(const bf16x8*)&lA[fbA + mi * 16 * BK + kk * 32];
      #pragma unroll
      for (int ni = 0; ni < 4; ++ni)
        bfr[ni] = *(const bf16x8*)&lB[fbB + ni * 16 * BK + kk * 32];
      #pragma unroll
      for (int mi = 0; mi < 4; ++mi)
        #pragma unroll
        for (int ni = 0; ni < 4; ++ni)
          acc[mi][ni] = __builtin_amdgcn_mfma_f32_16x16x32_bf16(af[mi], bfr[ni], acc[mi][ni], 0, 0, 0);
    }
  }

  #pragma unroll
  for (int ni = 0; ni < 4; ++ni) {
    int col = tn + wn + ni * 16 + l16;
    float bv = HAS_BIAS ? bias[col] : 0.f;
    #pragma unroll
    for (int mi = 0; mi < 4; ++mi)
      #pragma unroll
      for (int j = 0; j < 4; ++j) {
        int row = tm + wm + mi * 16 + kg * 4 + j;
        Cb[(long)row * ldc + col] = f2bf(acc[mi][ni][j] * alpha + bv);
      }
  }
}

// In-place LayerNorm over rows of 512 bf16. One wave/row. g,b f32.
__global__ __launch_bounds__(256)
void ln_rows(unsigned short* __restrict__ t, const float* __restrict__ g,
             const float* __restrict__ b)
{
  const int row = blockIdx.x * 4 + ((int)threadIdx.x >> 6);
  const int lane = (int)threadIdx.x & 63;
  unsigned short* p = t + (long)row * 512 + lane * 8;
  short8 rv = *(const short8*)p;
  float x[8];
  #pragma unroll
  for (int j = 0; j < 8; ++j) x[j] = bf2f((unsigned short)rv[j]);
  float s = 0.f;
  #pragma unroll
  for (int j = 0; j < 8; ++j) s += x[j];
  #pragma unroll
  for (int off = 32; off > 0; off >>= 1) s += __shfl_xor(s, off, 64);
  float mu = s * (1.f / 512.f);
  float vs = 0.f;
  #pragma unroll
  for (int j = 0; j < 8; ++j) { float d = x[j] - mu; vs += d * d; }
  #pragma unroll
  for (int off = 32; off > 0; off >>= 1) vs += __shfl_xor(vs, off, 64);
  float rs = rsqrtf(vs * (1.f / 512.f) + 1e-5f);
  f32x4 gv0 = *(const f32x4*)(g + lane * 8);
  f32x4 gv1 = *(const f32x4*)(g + lane * 8 + 4);
  f32x4 bv0 = *(const f32x4*)(b + lane * 8);
  f32x4 bv1 = *(const f32x4*)(b + lane * 8 + 4);
  short8 ov;
  #pragma unroll
  for (int j = 0; j < 4; ++j) ov[j] = (short)f2bf((x[j] - mu) * rs * gv0[j] + bv0[j]);
  #pragma unroll
  for (int j = 0; j < 4; ++j) ov[4 + j] = (short)f2bf((x[4 + j] - mu) * rs * gv1[j] + bv1[j]);
  *(short8*)p = ov;
}

// w = (val * gelu_exact(gate)) / max(||.||2, 1e-12)
__global__ __launch_bounds__(256)
void gate_norm(const unsigned short* __restrict__ h, unsigned short* __restrict__ w)
{
  const int row = blockIdx.x * 4 + ((int)threadIdx.x >> 6);
  const int lane = (int)threadIdx.x & 63;
  const unsigned short* hp = h + (long)row * 1024 + lane * 8;
  short8 vv = *(const short8*)hp;
  short8 gg = *(const short8*)(hp + 512);
  float wv[8];
  float ssq = 0.f;
  #pragma unroll
  for (int j = 0; j < 8; ++j) {
    float val = bf2f((unsigned short)vv[j]);
    float gt  = bf2f((unsigned short)gg[j]);
    float tt  = val * (0.5f * gt * (1.f + erff(gt * 0.70710678118654752f)));
    wv[j] = tt;
    ssq += tt * tt;
  }
  #pragma unroll
  for (int off = 32; off > 0; off >>= 1) ssq += __shfl_xor(ssq, off, 64);
  float scale = 1.f / fmaxf(sqrtf(ssq), 1e-12f);
  short8 ov;
  #pragma unroll
  for (int j = 0; j < 8; ++j) ov[j] = (short)f2bf(wv[j] * scale);
  *(short8*)(w + (long)row * 512 + lane * 8) = ov;
}

// v (B,S,E) bf16 -> vT (B*H, 512d, 512t)
__global__ __launch_bounds__(256)
void transpose_v(const unsigned short* __restrict__ v, unsigned short* __restrict__ vT)
{
  __shared__ alignas(16) unsigned short lt[64][72];
  const int bh = blockIdx.z;
  const int b = bh >> 3, hh = bh & 7;
  const int d0 = blockIdx.x * 64, t0 = blockIdx.y * 64;
  const int tid = (int)threadIdx.x;
  const unsigned short* src = v + (long)b * (512L * 4096L) + hh * 512;
  #pragma unroll
  for (int it = 0; it < 2; ++it) {
    int ci = it * 256 + tid;
    int r = ci >> 3, c8 = (ci & 7) * 8;
    *(short8*)&lt[r][c8] = *(const short8*)(src + (long)(t0 + r) * 4096 + d0 + c8);
  }
  __syncthreads();
  unsigned short* dst = vT + ((long)bh * 512 + d0) * 512 + t0;
  #pragma unroll
  for (int it = 0; it < 2; ++it) {
    int ci = it * 256 + tid;
    int rr = ci >> 3, c8 = (ci & 7) * 8;
    short8 o;
    #pragma unroll
    for (int j = 0; j < 8; ++j) o[j] = (short)lt[c8 + j][rr];
    *(short8*)(dst + (long)rr * 512 + c8) = o;
  }
}

extern "C" void kernel_launch(void* const* d_in, const int* in_sizes, int n_in,
                              void* d_out, int out_size, void* d_ws, size_t ws_size,
                              hipStream_t stream)
{
  (void)in_sizes; (void)n_in; (void)out_size; (void)ws_size;
  const float* x   = (const float*)d_in[0];
  const float* Wq  = (const float*)d_in[1];
  const float* bq  = (const float*)d_in[2];
  const float* Wk  = (const float*)d_in[3];
  const float* bk  = (const float*)d_in[4];
  const float* Wv  = (const float*)d_in[5];
  const float* bv  = (const float*)d_in[6];
  const float* g_q = (const float*)d_in[7];
  const float* b_q = (const float*)d_in[8];
  const float* g_k = (const float*)d_in[9];
  const float* b_k = (const float*)d_in[10];
  const float* Wg  = (const float*)d_in[11];
  const float* bg  = (const float*)d_in[12];
  const float* Wo  = (const float*)d_in[13];
  const float* bo  = (const float*)d_in[14];
  float* out = (float*)d_out;

  const long NE  = 33554432L;   // B*S*E
  const long NE2 = NE / 2;      // 4096*4096
  unsigned short* ws    = (unsigned short*)d_ws;
  // Layout (shorts): [xb:0..NE | Wslot:NE..1.5NE | qbuf:1.5..2.5 | kbuf:2.5..3.5 |
  //                   vbuf:3.5..4.5 | Wob:4.5..5 | Wgb:5NE.. ]   total 5.02*NE (337MB)
  unsigned short* xb    = ws;
  unsigned short* Wslot = ws + NE;
  unsigned short* qbuf  = ws + NE + NE2;
  unsigned short* kbuf  = ws + 2 * NE + NE2;
  unsigned short* vbuf  = ws + 3 * NE + NE2;
  unsigned short* Wob   = ws + 4 * NE + NE2;
  unsigned short* Wgb   = ws + 5 * NE;
  unsigned short* sbuf  = xb;                 // scores (q,k live elsewhere)
  unsigned short* vT    = qbuf;               // q dead after scores
  unsigned short* hbuf  = kbuf;               // spans kbuf+vbuf (2NE), both dead
  unsigned short* wbuf  = xb;                 // scores dead after h-GEMM
  unsigned short* obuf  = kbuf;               // h dead after gate_norm

  dim3 blk256(256), blk512(512);
  const float inv_sqrt_hd = 0.044194173824159216f;  // 1/sqrt(512)

  // conversions (W-slot reused per projection)
  cvt_bf16<<<16384, blk256, 0, stream>>>(x, xb, NE / 8);
  cvt_bf16<<<256, blk256, 0, stream>>>(Wg, Wgb, 524288L / 8);
  cvt_bf16<<<8192, blk256, 0, stream>>>(Wo, Wob, NE2 / 8);

  cvt_bf16<<<8192, blk256, 0, stream>>>(Wq, Wslot, NE2 / 8);
  gemm256<0, 1><<<512, blk512, 0, stream>>>(xb, Wslot, bq, qbuf,
      8192, 4096, 4096, 4096, 4096, 4096, 16);
  cvt_bf16<<<8192, blk256, 0, stream>>>(Wk, Wslot, NE2 / 8);
  gemm256<0, 1><<<512, blk512, 0, stream>>>(xb, Wslot, bk, kbuf,
      8192, 4096, 4096, 4096, 4096, 4096, 16);
  cvt_bf16<<<8192, blk256, 0, stream>>>(Wv, Wslot, NE2 / 8);
  gemm256<0, 1><<<512, blk512, 0, stream>>>(xb, Wslot, bv, vbuf,
      8192, 4096, 4096, 4096, 4096, 4096, 16);

  ln_rows<<<16384, blk256, 0, stream>>>(qbuf, g_q, b_q);
  ln_rows<<<16384, blk256, 0, stream>>>(kbuf, g_k, b_k);

  // scores = q @ k^T / sqrt(HD), per (b,h)  -> sbuf (=xb)
  gemm_bt<0><<<dim3(4, 4, 128), blk256, 0, stream>>>(qbuf, kbuf, nullptr, sbuf,
      512, 512, 512, 4096, 4096, 512,
      2097152L, 512L, 8, 2097152L, 512L, 8, 262144L, 0L, 1, inv_sqrt_hd);

  transpose_v<<<dim3(8, 8, 128), blk256, 0, stream>>>(vbuf, vT);

  // h = scores @ Wg^T + bg -> hbuf (=kbuf..vbuf)
  gemm_bt<1><<<dim3(8, 4, 128), blk256, 0, stream>>>(sbuf, Wgb, bg, hbuf,
      512, 1024, 512, 512, 512, 1024,
      262144L, 0L, 1, 0L, 0L, 1, 524288L, 0L, 1, 1.f);

  // w = normalize(val * gelu(gate)) -> wbuf (=xb)
  gate_norm<<<16384, blk256, 0, stream>>>(hbuf, wbuf);

  // attn_out = w @ vT^T -> obuf (=kbuf region), (B,S,E) layout
  gemm_bt<0><<<dim3(4, 4, 128), blk256, 0, stream>>>(wbuf, vT, nullptr, obuf,
      512, 512, 512, 512, 512, 4096,
      262144L, 0L, 1, 262144L, 0L, 1, 2097152L, 512L, 8, 1.f);

  // final = attn_out @ Wo^T + bo -> d_out (f32)
  gemm256<1, 1><<<512, blk512, 0, stream>>>(obuf, Wob, bo, out,
      8192, 4096, 4096, 4096, 4096, 4096, 16);
}